// Round 6
// baseline (590.937 us; speedup 1.0000x reference)
//
#include <hip/hip_runtime.h>

#define B_   2
#define S_   2048
#define H_   2560
#define NH_  8
#define NKV_ 4
#define D_   256
#define SW_  1024

// qkv row layout (fp16, stride 4096): [0,2048) Q heads, [2048,3072) K, [3072,4096) V
#define QKV_LD 4096

typedef __attribute__((ext_vector_type(8))) short    short8;
typedef __attribute__((ext_vector_type(8))) _Float16 half8;
typedef __attribute__((ext_vector_type(4))) _Float16 half4;
typedef __attribute__((ext_vector_type(4))) float    floatx4;
typedef __attribute__((ext_vector_type(2))) float    floatx2;

typedef unsigned int __attribute__((address_space(1))) as1_uint;
typedef unsigned int __attribute__((address_space(3))) as3_uint;

static __device__ __forceinline__ void async16(const void* g, void* l) {
    __builtin_amdgcn_global_load_lds((const as1_uint*)g, (as3_uint*)l, 16, 0, 0);
}

// ---------------------------------------------------------------------------
// Fused fp32 -> fp16 conversion for all 5 tensors (blockIdx.y selects tensor)
// ---------------------------------------------------------------------------
__global__ __launch_bounds__(256) void conv_all(
    const float* __restrict__ s0, const float* __restrict__ s1,
    const float* __restrict__ s2, const float* __restrict__ s3,
    const float* __restrict__ s4,
    _Float16* __restrict__ d0, _Float16* __restrict__ d1,
    _Float16* __restrict__ d2, _Float16* __restrict__ d3,
    _Float16* __restrict__ d4)
{
    const float* src; _Float16* dst; int n4;
    switch (blockIdx.y) {
        case 0:  src = s0; dst = d0; n4 = 4096 * 2560 / 4; break;   // hidden
        case 1:  src = s1; dst = d1; n4 = 2048 * 2560 / 4; break;   // Wq
        case 2:  src = s2; dst = d2; n4 = 1024 * 2560 / 4; break;   // Wk
        case 3:  src = s3; dst = d3; n4 = 1024 * 2560 / 4; break;   // Wv
        default: src = s4; dst = d4; n4 = 2560 * 2048 / 4; break;   // Wo
    }
    for (int i = blockIdx.x * 256 + threadIdx.x; i < n4; i += gridDim.x * 256) {
        floatx4 v = *(const floatx4*)(src + (size_t)i * 4);
        half4 h = { (_Float16)v.x, (_Float16)v.y, (_Float16)v.z, (_Float16)v.w };
        *(half4*)(dst + (size_t)i * 4) = h;
    }
}

// ---------------------------------------------------------------------------
// fp16 GEMM (m97 structure): C[M,N] = A[M,K] @ B[N,K]^T, both fp16 row-major,
// staged via global_load_lds width-16. 128x128 tile, BK=32, 4 waves,
// mfma_f32_16x16x32_f16. C fp16 (C_FP32=0) or fp32 (C_FP32=1).
// ---------------------------------------------------------------------------
template <int C_FP32>
__global__ __launch_bounds__(256, 2) void gemm_f16(
    const _Float16* __restrict__ A,
    const _Float16* __restrict__ Bm,
    void* __restrict__ Cv,
    int M, int N, int K)
{
    __shared__ __align__(16) _Float16 As[128 * 32];
    __shared__ __align__(16) _Float16 Bs[128 * 32];

    const int tid  = threadIdx.x;
    const int lane = tid & 63, w = tid >> 6;
    const int wr = w >> 1, wc = w & 1;
    const int quad = lane >> 4, l16 = lane & 15;
    const int mBase = blockIdx.y * 128, nBase = blockIdx.x * 128;

    floatx4 acc[4][4];
    const floatx4 fzero = {0.f, 0.f, 0.f, 0.f};
#pragma unroll
    for (int i = 0; i < 4; ++i)
#pragma unroll
        for (int j = 0; j < 4; ++j) acc[i][j] = fzero;

    const int sRow = lane >> 2;
    const int sCol = (lane & 3) * 8;
    const size_t aRow = (size_t)(mBase + w * 32 + sRow);
    const size_t bRow = (size_t)(nBase + w * 32 + sRow);

    for (int kk = 0; kk < K; kk += 32) {
#pragma unroll
        for (int i = 0; i < 2; ++i) {
            async16(A  + (aRow + i * 16) * K + kk + sCol, &As[(w * 32 + i * 16) * 32]);
            async16(Bm + (bRow + i * 16) * K + kk + sCol, &Bs[(w * 32 + i * 16) * 32]);
        }
        __syncthreads();
        half8 af[4], bfv[4];
#pragma unroll
        for (int i = 0; i < 4; ++i)
            af[i] = *(const half8*)&As[(wr * 64 + i * 16 + l16) * 32 + quad * 8];
#pragma unroll
        for (int j = 0; j < 4; ++j)
            bfv[j] = *(const half8*)&Bs[(wc * 64 + j * 16 + l16) * 32 + quad * 8];
#pragma unroll
        for (int i = 0; i < 4; ++i)
#pragma unroll
            for (int j = 0; j < 4; ++j)
                acc[i][j] = __builtin_amdgcn_mfma_f32_16x16x32_f16(af[i], bfv[j], acc[i][j], 0, 0, 0);
        __syncthreads();
    }

    // epilogue: C/D layout col=lane&15, row=quad*4+reg (m89-verified)
#pragma unroll
    for (int i = 0; i < 4; ++i) {
        const int row0 = mBase + wr * 64 + i * 16 + quad * 4;
#pragma unroll
        for (int j = 0; j < 4; ++j) {
            const int col = nBase + wc * 64 + j * 16 + l16;
#pragma unroll
            for (int r = 0; r < 4; ++r) {
                const size_t idx = (size_t)(row0 + r) * N + col;
                if (C_FP32) ((float*)Cv)[idx] = acc[i][j][r];
                else        ((_Float16*)Cv)[idx] = (_Float16)acc[i][j][r];
            }
        }
    }
}

// ---------------------------------------------------------------------------
// IN-PLACE RMSNorm (per 256-dim head vector) + RoPE for q/k, plain RMS for v.
// ---------------------------------------------------------------------------
__global__ __launch_bounds__(256) void rmsrope_inplace(
    _Float16* __restrict__ qkv,        // [4096][4096] fp16
    const float* __restrict__ cosT,    // [S][D] fp32
    const float* __restrict__ sinT,
    const float* __restrict__ qw,      // [D] fp32
    const float* __restrict__ kw)
{
    const int t = blockIdx.x;                // b*S + s
    const int s = t & (S_ - 1);
    const int tid = threadIdx.x, lane = tid & 63, w = tid >> 6;
    _Float16* row = qkv + (size_t)t * QKV_LD;
    const int d0 = lane * 2, d1 = 128 + lane * 2;

    floatx2 c0 = *(const floatx2*)(cosT + (size_t)s * D_ + d0);
    floatx2 c1 = *(const floatx2*)(cosT + (size_t)s * D_ + d1);
    floatx2 s0 = *(const floatx2*)(sinT + (size_t)s * D_ + d0);
    floatx2 s1 = *(const floatx2*)(sinT + (size_t)s * D_ + d1);
    floatx2 qw0 = *(const floatx2*)(qw + d0), qw1 = *(const floatx2*)(qw + d1);
    floatx2 kw0 = *(const floatx2*)(kw + d0), kw1 = *(const floatx2*)(kw + d1);

#pragma unroll
    for (int p = 0; p < 4; ++p) {
        const int v = w + p * 4;             // 0..15, wave-uniform
        _Float16* x = row + v * D_;
        float x0a = (float)x[d0], x0b = (float)x[d0 + 1];
        float x1a = (float)x[d1], x1b = (float)x[d1 + 1];
        float ss = x0a * x0a + x0b * x0b + x1a * x1a + x1b * x1b;
#pragma unroll
        for (int off = 32; off > 0; off >>= 1) ss += __shfl_xor(ss, off, 64);
        const float rinv = rsqrtf(ss * (1.0f / 256.0f) + 1e-6f);
        if (v < 8) {
            const float y0a = x0a * rinv * (1.f + qw0.x), y0b = x0b * rinv * (1.f + qw0.y);
            const float y1a = x1a * rinv * (1.f + qw1.x), y1b = x1b * rinv * (1.f + qw1.y);
            x[d0] = (_Float16)(y0a * c0.x - y1a * s0.x);
            x[d0 + 1] = (_Float16)(y0b * c0.y - y1b * s0.y);
            x[d1] = (_Float16)(y1a * c1.x + y0a * s1.x);
            x[d1 + 1] = (_Float16)(y1b * c1.y + y0b * s1.y);
        } else if (v < 12) {
            const float y0a = x0a * rinv * (1.f + kw0.x), y0b = x0b * rinv * (1.f + kw0.y);
            const float y1a = x1a * rinv * (1.f + kw1.x), y1b = x1b * rinv * (1.f + kw1.y);
            x[d0] = (_Float16)(y0a * c0.x - y1a * s0.x);
            x[d0 + 1] = (_Float16)(y0b * c0.y - y1b * s0.y);
            x[d1] = (_Float16)(y1a * c1.x + y0a * s1.x);
            x[d1 + 1] = (_Float16)(y1b * c1.y + y0b * s1.y);
        } else {
            x[d0] = (_Float16)(x0a * rinv);
            x[d0 + 1] = (_Float16)(x0b * rinv);
            x[d1] = (_Float16)(x1a * rinv);
            x[d1 + 1] = (_Float16)(x1b * rinv);
        }
    }
}

// ---------------------------------------------------------------------------
// Transpose V out of qkv: [b][s][3072+kvh*256+d] -> Vt[b][kvh][d][s]
// 64x64 LDS tiles, pad 66 (reads bank-clean, writes 2-way = free).
// ---------------------------------------------------------------------------
__global__ __launch_bounds__(256) void transpose_v(
    const _Float16* __restrict__ qkv, _Float16* __restrict__ Vt)
{
    __shared__ _Float16 tile[64][66];
    const int s0 = blockIdx.x * 64;
    const int dd0 = blockIdx.y * 64;
    const int bk = blockIdx.z;               // b*NKV + kvh
    const int b = bk >> 2, kvh = bk & 3;
    const _Float16* src = qkv + (size_t)(b * S_) * QKV_LD + 3072 + kvh * D_;
    _Float16* dst = Vt + (size_t)bk * D_ * S_;
    const int tx = threadIdx.x & 63, ty = threadIdx.x >> 6;
    for (int r = ty; r < 64; r += 4)
        tile[r][tx] = src[(size_t)(s0 + r) * QKV_LD + dd0 + tx];
    __syncthreads();
    for (int r = ty; r < 64; r += 4)
        dst[(size_t)(dd0 + r) * S_ + s0 + tx] = tile[tx][r];
}

// ---------------------------------------------------------------------------
// Flash attention v2 — BARRIER-FREE. Causal + sliding window (analytic),
// scale = 1.0. K and V^T MFMA B-fragments load directly from global (L1/L2
// absorb the 4x cross-wave reuse); only P round-trips wave-private LDS.
// 64 queries/block (wave = 16 rows), 32-key tiles, f16 MFMA.
// ---------------------------------------------------------------------------
#define PS_STRIDE 40

__global__ __launch_bounds__(256, 2) void attn_kernel(
    const _Float16* __restrict__ qkv,  // [B*S][4096] fp16 (post rms+rope)
    const _Float16* __restrict__ Vt,   // [B][NKV][D][S] fp16
    _Float16* __restrict__ Oa)         // [B*S][NH*D] fp16
{
    __shared__ __align__(16) _Float16 Ps[4][16 * PS_STRIDE];

    const int qb = blockIdx.x * 64;
    const int h = blockIdx.y, b = blockIdx.z;
    const int kvh = h >> 1;                       // repeat_interleave(2)
    const int tid = threadIdx.x, lane = tid & 63, w = tid >> 6;
    const int quad = lane >> 4, l16 = lane & 15;

    // Q fragments: A-layout m=lane&15, k=quad*8+j
    const _Float16* Qrow = qkv + ((size_t)(b * S_ + qb + w * 16 + l16)) * QKV_LD + h * D_;
    half8 qf[8];
#pragma unroll
    for (int kst = 0; kst < 8; ++kst)
        qf[kst] = *(const half8*)(Qrow + kst * 32 + quad * 8);

    floatx4 o[16];
    const floatx4 fzero = {0.f, 0.f, 0.f, 0.f};
#pragma unroll
    for (int dt = 0; dt < 16; ++dt) o[dt] = fzero;
    float mrow[4] = {-1e30f, -1e30f, -1e30f, -1e30f};
    float lrow[4] = {0.f, 0.f, 0.f, 0.f};

    const _Float16* Kbase  = qkv + (size_t)(b * S_) * QKV_LD + 2048 + kvh * D_;
    const _Float16* Vtbase = Vt + (size_t)(b * NKV_ + kvh) * D_ * S_;
    const int kb_start = (qb >= SW_) ? qb - SW_ : 0;
    const int kb_end = qb + 32;  // inclusive; last tile covers keys qb+32..qb+63

    for (int kb = kb_start; kb <= kb_end; kb += 32) {
        // ---- QK^T with direct-global K B-fragments (B[n=key][k=d]) ----
        half8 kf[2][8];
#pragma unroll
        for (int jt = 0; jt < 2; ++jt) {
            const _Float16* kr = Kbase + (size_t)(kb + jt * 16 + l16) * QKV_LD + quad * 8;
#pragma unroll
            for (int kst = 0; kst < 8; ++kst)
                kf[jt][kst] = *(const half8*)(kr + kst * 32);
        }
        floatx4 sacc[2];
        sacc[0] = fzero; sacc[1] = fzero;
#pragma unroll
        for (int jt = 0; jt < 2; ++jt)
#pragma unroll
            for (int kst = 0; kst < 8; ++kst)
                sacc[jt] = __builtin_amdgcn_mfma_f32_16x16x32_f16(qf[kst], kf[jt][kst], sacc[jt], 0, 0, 0);

        // ---- analytic mask + online softmax (row = quad*4+reg, col = lane&15) ----
        const int q0 = qb + w * 16 + quad * 4;
        float sval[2][4], tmax[4];
#pragma unroll
        for (int r = 0; r < 4; ++r) tmax[r] = -1e30f;
#pragma unroll
        for (int jt = 0; jt < 2; ++jt) {
            const int kg = kb + jt * 16 + l16;
#pragma unroll
            for (int r = 0; r < 4; ++r) {
                const int qg = q0 + r;
                const bool ok = (kg <= qg) && (kg + SW_ > qg);
                const float vv = ok ? sacc[jt][r] : -1e30f;
                sval[jt][r] = vv;
                tmax[r] = fmaxf(tmax[r], vv);
            }
        }
#pragma unroll
        for (int r = 0; r < 4; ++r) {
#pragma unroll
            for (int off = 1; off < 16; off <<= 1)
                tmax[r] = fmaxf(tmax[r], __shfl_xor(tmax[r], off, 64));
            const float mnew = fmaxf(mrow[r], tmax[r]);
            const float alpha = __expf(mrow[r] - mnew);
            mrow[r] = mnew;
            lrow[r] *= alpha;
            tmax[r] = alpha;                 // reuse as alpha
        }
        float rsum[4] = {0.f, 0.f, 0.f, 0.f};
#pragma unroll
        for (int jt = 0; jt < 2; ++jt)
#pragma unroll
            for (int r = 0; r < 4; ++r) {
                float pv = __expf(sval[jt][r] - mrow[r]);
                pv = (sval[jt][r] <= -1e29f) ? 0.0f : pv;   // masked -> exact 0
                rsum[r] += pv;
                Ps[w][(quad * 4 + r) * PS_STRIDE + jt * 16 + l16] = (_Float16)pv;
            }
#pragma unroll
        for (int r = 0; r < 4; ++r) {
#pragma unroll
            for (int off = 1; off < 16; off <<= 1)
                rsum[r] += __shfl_xor(rsum[r], off, 64);
            lrow[r] += rsum[r];
        }
        // rescale O by alpha
#pragma unroll
        for (int dt = 0; dt < 16; ++dt)
#pragma unroll
            for (int r = 0; r < 4; ++r) o[dt][r] *= tmax[r];

        // ---- O += P V with direct-global V^T B-fragments (B[n=d][k=key]) ----
        // P: wave-private LDS round-trip C-layout -> A-layout (no barrier:
        // same-wave ds ordering via compiler lgkmcnt)
        half8 pa = *(const half8*)&Ps[w][l16 * PS_STRIDE + quad * 8];
        half8 vf[16];
#pragma unroll
        for (int dt = 0; dt < 16; ++dt)
            vf[dt] = *(const half8*)(Vtbase + (size_t)(dt * 16 + l16) * S_ + kb + quad * 8);
#pragma unroll
        for (int dt = 0; dt < 16; ++dt)
            o[dt] = __builtin_amdgcn_mfma_f32_16x16x32_f16(pa, vf[dt], o[dt], 0, 0, 0);
    }

    // epilogue: divide by l, store fp16 [B*S][NH*D]
    const int qrow = qb + w * 16 + quad * 4;
#pragma unroll
    for (int r = 0; r < 4; ++r) {
        const float inv = (lrow[r] > 0.f) ? (1.0f / lrow[r]) : 0.f;
        _Float16* orow = Oa + ((size_t)(b * S_ + qrow + r)) * (NH_ * D_) + h * D_;
#pragma unroll
        for (int dt = 0; dt < 16; ++dt)
            orow[dt * 16 + l16] = (_Float16)(o[dt][r] * inv);
    }
}

// ---------------------------------------------------------------------------
extern "C" void kernel_launch(void* const* d_in, const int* in_sizes, int n_in,
                              void* d_out, int out_size, void* d_ws, size_t ws_size,
                              hipStream_t stream)
{
    (void)in_sizes; (void)n_in; (void)out_size; (void)ws_size;
    const float* hid  = (const float*)d_in[0];
    // d_in[1] = attention_mask (unused: analytic causal+window mask is exact)
    const float* cosT = (const float*)d_in[2];
    const float* sinT = (const float*)d_in[3];
    const float* Wq   = (const float*)d_in[4];
    const float* Wk   = (const float*)d_in[5];
    const float* Wv   = (const float*)d_in[6];
    const float* Wo   = (const float*)d_in[7];
    const float* qw   = (const float*)d_in[8];
    const float* kw   = (const float*)d_in[9];
    float* out = (float*)d_out;

    // workspace layout (bytes; ~106 MB total)
    char* ws = (char*)d_ws;
    _Float16* qkv  = (_Float16*)(ws);                      // 33,554,432  [4096][4096]
    _Float16* attn = (_Float16*)(ws + 33554432ull);        // 16,777,216  [4096][2048]
    _Float16* hidH = (_Float16*)(ws + 50331648ull);        // 20,971,520  [4096][2560]
    _Float16* wQKV = (_Float16*)(ws + 71303168ull);        // 20,971,520  [4096][2560]
    _Float16* woH  = (_Float16*)(ws + 92274688ull);        // 10,485,760  [2560][2048]
    _Float16* Vt   = (_Float16*)(ws + 102760448ull);       //  8,388,608  [B][NKV][D][S]

    // 0) all fp32 -> fp16 conversions in one launch
    conv_all<<<dim3(512, 5), 256, 0, stream>>>(
        hid, Wq, Wk, Wv, Wo,
        hidH, wQKV, wQKV + (size_t)2048 * 2560, wQKV + (size_t)3072 * 2560, woH);

    // 1) QKV projection (fp16 MFMA): -> fp16 [4096][4096]
    gemm_f16<0><<<dim3(32, 32), 256, 0, stream>>>(hidH, wQKV, qkv, 4096, 4096, 2560);
    // 2) in-place RMSNorm + RoPE on qkv
    rmsrope_inplace<<<4096, 256, 0, stream>>>(qkv, cosT, sinT, qw, kw);
    // 3) V transpose -> Vt [b][kvh][d][s]
    transpose_v<<<dim3(32, 4, 8), 256, 0, stream>>>(qkv, Vt);
    // 4) flash attention (barrier-free): -> attn [4096][2048] fp16
    attn_kernel<<<dim3(32, 8, 2), 256, 0, stream>>>(qkv, Vt, attn);
    // 5) output projection: fp16 [4096,2048] @ Wo^T -> fp32 out [4096][2560]
    gemm_f16<1><<<dim3(20, 32), 256, 0, stream>>>(attn, woH, out, 4096, 2560, 2048);
}

// Round 7
// 442.652 us; speedup vs baseline: 1.3350x; 1.3350x over previous
//
#include <hip/hip_runtime.h>

#define B_   2
#define S_   2048
#define H_   2560
#define NH_  8
#define NKV_ 4
#define D_   256
#define SW_  1024

// qkv row layout (fp16, stride 4096): [0,2048) Q heads, [2048,3072) K, [3072,4096) V
#define QKV_LD 4096

typedef __attribute__((ext_vector_type(8))) short    short8;
typedef __attribute__((ext_vector_type(8))) _Float16 half8;
typedef __attribute__((ext_vector_type(4))) _Float16 half4;
typedef __attribute__((ext_vector_type(4))) float    floatx4;
typedef __attribute__((ext_vector_type(2))) float    floatx2;

typedef unsigned int __attribute__((address_space(1))) as1_uint;
typedef unsigned int __attribute__((address_space(3))) as3_uint;

static __device__ __forceinline__ void async16(const void* g, void* l) {
    __builtin_amdgcn_global_load_lds((const as1_uint*)g, (as3_uint*)l, 16, 0, 0);
}

// ---------------------------------------------------------------------------
// Fused fp32 -> fp16 conversion for all 5 tensors (blockIdx.y selects tensor)
// ---------------------------------------------------------------------------
__global__ __launch_bounds__(256) void conv_all(
    const float* __restrict__ s0, const float* __restrict__ s1,
    const float* __restrict__ s2, const float* __restrict__ s3,
    const float* __restrict__ s4,
    _Float16* __restrict__ d0, _Float16* __restrict__ d1,
    _Float16* __restrict__ d2, _Float16* __restrict__ d3,
    _Float16* __restrict__ d4)
{
    const float* src; _Float16* dst; int n4;
    switch (blockIdx.y) {
        case 0:  src = s0; dst = d0; n4 = 4096 * 2560 / 4; break;   // hidden
        case 1:  src = s1; dst = d1; n4 = 2048 * 2560 / 4; break;   // Wq
        case 2:  src = s2; dst = d2; n4 = 1024 * 2560 / 4; break;   // Wk
        case 3:  src = s3; dst = d3; n4 = 1024 * 2560 / 4; break;   // Wv
        default: src = s4; dst = d4; n4 = 2560 * 2048 / 4; break;   // Wo
    }
    for (int i = blockIdx.x * 256 + threadIdx.x; i < n4; i += gridDim.x * 256) {
        floatx4 v = *(const floatx4*)(src + (size_t)i * 4);
        half4 h = { (_Float16)v.x, (_Float16)v.y, (_Float16)v.z, (_Float16)v.w };
        *(half4*)(dst + (size_t)i * 4) = h;
    }
}

// ---------------------------------------------------------------------------
// fp16 GEMM (m97 structure): C[M,N] = A[M,K] @ B[N,K]^T, both fp16 row-major,
// staged via global_load_lds width-16. 128x128 tile, BK=32, 4 waves,
// mfma_f32_16x16x32_f16. C fp16 (C_FP32=0) or fp32 (C_FP32=1).
// ---------------------------------------------------------------------------
template <int C_FP32>
__global__ __launch_bounds__(256, 2) void gemm_f16(
    const _Float16* __restrict__ A,
    const _Float16* __restrict__ Bm,
    void* __restrict__ Cv,
    int M, int N, int K)
{
    __shared__ __align__(16) _Float16 As[128 * 32];
    __shared__ __align__(16) _Float16 Bs[128 * 32];

    const int tid  = threadIdx.x;
    const int lane = tid & 63, w = tid >> 6;
    const int wr = w >> 1, wc = w & 1;
    const int quad = lane >> 4, l16 = lane & 15;
    const int mBase = blockIdx.y * 128, nBase = blockIdx.x * 128;

    floatx4 acc[4][4];
    const floatx4 fzero = {0.f, 0.f, 0.f, 0.f};
#pragma unroll
    for (int i = 0; i < 4; ++i)
#pragma unroll
        for (int j = 0; j < 4; ++j) acc[i][j] = fzero;

    const int sRow = lane >> 2;
    const int sCol = (lane & 3) * 8;
    const size_t aRow = (size_t)(mBase + w * 32 + sRow);
    const size_t bRow = (size_t)(nBase + w * 32 + sRow);

    for (int kk = 0; kk < K; kk += 32) {
#pragma unroll
        for (int i = 0; i < 2; ++i) {
            async16(A  + (aRow + i * 16) * K + kk + sCol, &As[(w * 32 + i * 16) * 32]);
            async16(Bm + (bRow + i * 16) * K + kk + sCol, &Bs[(w * 32 + i * 16) * 32]);
        }
        __syncthreads();
        half8 af[4], bfv[4];
#pragma unroll
        for (int i = 0; i < 4; ++i)
            af[i] = *(const half8*)&As[(wr * 64 + i * 16 + l16) * 32 + quad * 8];
#pragma unroll
        for (int j = 0; j < 4; ++j)
            bfv[j] = *(const half8*)&Bs[(wc * 64 + j * 16 + l16) * 32 + quad * 8];
#pragma unroll
        for (int i = 0; i < 4; ++i)
#pragma unroll
            for (int j = 0; j < 4; ++j)
                acc[i][j] = __builtin_amdgcn_mfma_f32_16x16x32_f16(af[i], bfv[j], acc[i][j], 0, 0, 0);
        __syncthreads();
    }

    // epilogue: C/D layout col=lane&15, row=quad*4+reg (m89-verified)
#pragma unroll
    for (int i = 0; i < 4; ++i) {
        const int row0 = mBase + wr * 64 + i * 16 + quad * 4;
#pragma unroll
        for (int j = 0; j < 4; ++j) {
            const int col = nBase + wc * 64 + j * 16 + l16;
#pragma unroll
            for (int r = 0; r < 4; ++r) {
                const size_t idx = (size_t)(row0 + r) * N + col;
                if (C_FP32) ((float*)Cv)[idx] = acc[i][j][r];
                else        ((_Float16*)Cv)[idx] = (_Float16)acc[i][j][r];
            }
        }
    }
}

// ---------------------------------------------------------------------------
// IN-PLACE RMSNorm (per 256-dim head vector) + RoPE for q/k, plain RMS for v.
// ---------------------------------------------------------------------------
__global__ __launch_bounds__(256) void rmsrope_inplace(
    _Float16* __restrict__ qkv,        // [4096][4096] fp16
    const float* __restrict__ cosT,    // [S][D] fp32
    const float* __restrict__ sinT,
    const float* __restrict__ qw,      // [D] fp32
    const float* __restrict__ kw)
{
    const int t = blockIdx.x;                // b*S + s
    const int s = t & (S_ - 1);
    const int tid = threadIdx.x, lane = tid & 63, w = tid >> 6;
    _Float16* row = qkv + (size_t)t * QKV_LD;
    const int d0 = lane * 2, d1 = 128 + lane * 2;

    floatx2 c0 = *(const floatx2*)(cosT + (size_t)s * D_ + d0);
    floatx2 c1 = *(const floatx2*)(cosT + (size_t)s * D_ + d1);
    floatx2 s0 = *(const floatx2*)(sinT + (size_t)s * D_ + d0);
    floatx2 s1 = *(const floatx2*)(sinT + (size_t)s * D_ + d1);
    floatx2 qw0 = *(const floatx2*)(qw + d0), qw1 = *(const floatx2*)(qw + d1);
    floatx2 kw0 = *(const floatx2*)(kw + d0), kw1 = *(const floatx2*)(kw + d1);

#pragma unroll
    for (int p = 0; p < 4; ++p) {
        const int v = w + p * 4;             // 0..15, wave-uniform
        _Float16* x = row + v * D_;
        float x0a = (float)x[d0], x0b = (float)x[d0 + 1];
        float x1a = (float)x[d1], x1b = (float)x[d1 + 1];
        float ss = x0a * x0a + x0b * x0b + x1a * x1a + x1b * x1b;
#pragma unroll
        for (int off = 32; off > 0; off >>= 1) ss += __shfl_xor(ss, off, 64);
        const float rinv = rsqrtf(ss * (1.0f / 256.0f) + 1e-6f);
        if (v < 8) {
            const float y0a = x0a * rinv * (1.f + qw0.x), y0b = x0b * rinv * (1.f + qw0.y);
            const float y1a = x1a * rinv * (1.f + qw1.x), y1b = x1b * rinv * (1.f + qw1.y);
            x[d0] = (_Float16)(y0a * c0.x - y1a * s0.x);
            x[d0 + 1] = (_Float16)(y0b * c0.y - y1b * s0.y);
            x[d1] = (_Float16)(y1a * c1.x + y0a * s1.x);
            x[d1 + 1] = (_Float16)(y1b * c1.y + y0b * s1.y);
        } else if (v < 12) {
            const float y0a = x0a * rinv * (1.f + kw0.x), y0b = x0b * rinv * (1.f + kw0.y);
            const float y1a = x1a * rinv * (1.f + kw1.x), y1b = x1b * rinv * (1.f + kw1.y);
            x[d0] = (_Float16)(y0a * c0.x - y1a * s0.x);
            x[d0 + 1] = (_Float16)(y0b * c0.y - y1b * s0.y);
            x[d1] = (_Float16)(y1a * c1.x + y0a * s1.x);
            x[d1 + 1] = (_Float16)(y1b * c1.y + y0b * s1.y);
        } else {
            x[d0] = (_Float16)(x0a * rinv);
            x[d0 + 1] = (_Float16)(x0b * rinv);
            x[d1] = (_Float16)(x1a * rinv);
            x[d1 + 1] = (_Float16)(x1b * rinv);
        }
    }
}

// ---------------------------------------------------------------------------
// Transpose V out of qkv: [b][s][3072+kvh*256+d] -> Vt[b][kvh][d][s]
// ---------------------------------------------------------------------------
__global__ __launch_bounds__(256) void transpose_v(
    const _Float16* __restrict__ qkv, _Float16* __restrict__ Vt)
{
    __shared__ _Float16 tile[64][66];
    const int s0 = blockIdx.x * 64;
    const int dd0 = blockIdx.y * 64;
    const int bk = blockIdx.z;               // b*NKV + kvh
    const int b = bk >> 2, kvh = bk & 3;
    const _Float16* src = qkv + (size_t)(b * S_) * QKV_LD + 3072 + kvh * D_;
    _Float16* dst = Vt + (size_t)bk * D_ * S_;
    const int tx = threadIdx.x & 63, ty = threadIdx.x >> 6;
    for (int r = ty; r < 64; r += 4)
        tile[r][tx] = src[(size_t)(s0 + r) * QKV_LD + dd0 + tx];
    __syncthreads();
    for (int r = ty; r < 64; r += 4)
        dst[(size_t)(dd0 + r) * S_ + s0 + tx] = tile[tx][r];
}

// ---------------------------------------------------------------------------
// Flash attention v3: async16-staged K/V^T tiles, double-buffered LDS, one
// barrier per K-tile. K tile stored with per-key chunk rotation (read chunk
// (kst*4+quad+key)&31 holds global chunk kst*4+quad) -> bank-floor reads
// with zero padding. V^T tile flat [256 d][32 keys] (64B rows spread banks
// naturally). Causal + sliding-window analytic mask, scale=1.0.
// ---------------------------------------------------------------------------
#define PS_STRIDE 40

__global__ __launch_bounds__(256, 2) void attn_kernel(
    const _Float16* __restrict__ qkv,  // [B*S][4096] fp16 (post rms+rope)
    const _Float16* __restrict__ Vt,   // [B][NKV][D][S] fp16
    _Float16* __restrict__ Oa)         // [B*S][NH*D] fp16
{
    __shared__ __align__(16) _Float16 Ks[2][32 * 256];   // 2 x 16 KB
    __shared__ __align__(16) _Float16 Vs[2][256 * 32];   // 2 x 16 KB
    __shared__ __align__(16) _Float16 Ps[4][16 * PS_STRIDE];

    const int qb = blockIdx.x * 64;
    const int h = blockIdx.y, b = blockIdx.z;
    const int kvh = h >> 1;                       // repeat_interleave(2)
    const int tid = threadIdx.x, lane = tid & 63, w = tid >> 6;
    const int quad = lane >> 4, l16 = lane & 15;

    // Q fragments: A-layout m=lane&15, k=quad*8+j
    const _Float16* Qrow = qkv + ((size_t)(b * S_ + qb + w * 16 + l16)) * QKV_LD + h * D_;
    half8 qf[8];
#pragma unroll
    for (int kst = 0; kst < 8; ++kst)
        qf[kst] = *(const half8*)(Qrow + kst * 32 + quad * 8);

    floatx4 o[16];
    const floatx4 fzero = {0.f, 0.f, 0.f, 0.f};
#pragma unroll
    for (int dt = 0; dt < 16; ++dt) o[dt] = fzero;
    float mrow[4] = {-1e30f, -1e30f, -1e30f, -1e30f};
    float lrow[4] = {0.f, 0.f, 0.f, 0.f};

    const _Float16* Kbase  = qkv + (size_t)(b * S_) * QKV_LD + 2048 + kvh * D_;
    const _Float16* Vtbase = Vt + (size_t)(b * NKV_ + kvh) * D_ * S_;
    const int kb_start = (qb >= SW_) ? qb - SW_ : 0;
    const int kb_end = qb + 32;  // inclusive; last tile covers keys qb+32..qb+63

    // staging lambda: K with per-key chunk rotation, V^T flat
    auto stage = [&](int kb, int bufi) {
#pragma unroll
        for (int p = 0; p < 4; ++p) {
            const int keyl = w * 8 + p * 2 + (lane >> 5);     // 0..31
            const int g = ((lane & 31) - keyl) & 31;          // rotated source chunk
            async16(Kbase + (size_t)(kb + keyl) * QKV_LD + g * 8,
                    &Ks[bufi][(w * 8 + p * 2) * 256]);
        }
#pragma unroll
        for (int p = 0; p < 4; ++p) {
            const int drow = w * 64 + p * 16 + (lane >> 2);   // 0..255
            const int q = lane & 3;
            async16(Vtbase + (size_t)drow * S_ + kb + q * 8,
                    &Vs[bufi][(w * 64 + p * 16) * 32]);
        }
    };

    int buf = 0;
    stage(kb_start, 0);

    for (int kb = kb_start; kb <= kb_end; kb += 32) {
        __syncthreads();                       // drains async16 for this buf
        if (kb + 32 <= kb_end) stage(kb + 32, buf ^ 1);

        // ---- S = Q K^T (wave: 16 queries x 32 keys), rotated K reads ----
        floatx4 sacc[2];
        sacc[0] = fzero; sacc[1] = fzero;
#pragma unroll
        for (int jt = 0; jt < 2; ++jt) {
            const int keyl = jt * 16 + l16;
#pragma unroll
            for (int kst = 0; kst < 8; ++kst) {
                const int crot = (kst * 4 + quad + keyl) & 31;
                half8 kf = *(const half8*)&Ks[buf][keyl * 256 + crot * 8];
                sacc[jt] = __builtin_amdgcn_mfma_f32_16x16x32_f16(qf[kst], kf, sacc[jt], 0, 0, 0);
            }
        }

        // ---- analytic mask + online softmax (row = quad*4+reg, col = lane&15) ----
        const int q0 = qb + w * 16 + quad * 4;
        float sval[2][4], tmax[4];
#pragma unroll
        for (int r = 0; r < 4; ++r) tmax[r] = -1e30f;
#pragma unroll
        for (int jt = 0; jt < 2; ++jt) {
            const int kg = kb + jt * 16 + l16;
#pragma unroll
            for (int r = 0; r < 4; ++r) {
                const int qg = q0 + r;
                const bool ok = (kg <= qg) && (kg + SW_ > qg);
                const float vv = ok ? sacc[jt][r] : -1e30f;
                sval[jt][r] = vv;
                tmax[r] = fmaxf(tmax[r], vv);
            }
        }
#pragma unroll
        for (int r = 0; r < 4; ++r) {
#pragma unroll
            for (int off = 1; off < 16; off <<= 1)
                tmax[r] = fmaxf(tmax[r], __shfl_xor(tmax[r], off, 64));
            const float mnew = fmaxf(mrow[r], tmax[r]);
            const float alpha = __expf(mrow[r] - mnew);
            mrow[r] = mnew;
            lrow[r] *= alpha;
            tmax[r] = alpha;                 // reuse as alpha
        }
        float rsum[4] = {0.f, 0.f, 0.f, 0.f};
#pragma unroll
        for (int jt = 0; jt < 2; ++jt)
#pragma unroll
            for (int r = 0; r < 4; ++r) {
                float pv = __expf(sval[jt][r] - mrow[r]);
                pv = (sval[jt][r] <= -1e29f) ? 0.0f : pv;   // masked -> exact 0
                rsum[r] += pv;
                Ps[w][(quad * 4 + r) * PS_STRIDE + jt * 16 + l16] = (_Float16)pv;
            }
#pragma unroll
        for (int r = 0; r < 4; ++r) {
#pragma unroll
            for (int off = 1; off < 16; off <<= 1)
                rsum[r] += __shfl_xor(rsum[r], off, 64);
            lrow[r] += rsum[r];
        }
        // rescale O by alpha
#pragma unroll
        for (int dt = 0; dt < 16; ++dt)
#pragma unroll
            for (int r = 0; r < 4; ++r) o[dt][r] *= tmax[r];

        // ---- O += P V (P via wave-private LDS round-trip, no barrier) ----
        half8 pa = *(const half8*)&Ps[w][l16 * PS_STRIDE + quad * 8];
#pragma unroll
        for (int dt = 0; dt < 16; ++dt) {
            half8 vf = *(const half8*)&Vs[buf][(dt * 16 + l16) * 32 + quad * 8];
            o[dt] = __builtin_amdgcn_mfma_f32_16x16x32_f16(pa, vf, o[dt], 0, 0, 0);
        }
        buf ^= 1;
    }

    // epilogue: divide by l, store fp16 [B*S][NH*D]
    const int qrow = qb + w * 16 + quad * 4;
#pragma unroll
    for (int r = 0; r < 4; ++r) {
        const float inv = (lrow[r] > 0.f) ? (1.0f / lrow[r]) : 0.f;
        _Float16* orow = Oa + ((size_t)(b * S_ + qrow + r)) * (NH_ * D_) + h * D_;
#pragma unroll
        for (int dt = 0; dt < 16; ++dt)
            orow[dt * 16 + l16] = (_Float16)(o[dt][r] * inv);
    }
}

// ---------------------------------------------------------------------------
extern "C" void kernel_launch(void* const* d_in, const int* in_sizes, int n_in,
                              void* d_out, int out_size, void* d_ws, size_t ws_size,
                              hipStream_t stream)
{
    (void)in_sizes; (void)n_in; (void)out_size; (void)ws_size;
    const float* hid  = (const float*)d_in[0];
    // d_in[1] = attention_mask (unused: analytic causal+window mask is exact)
    const float* cosT = (const float*)d_in[2];
    const float* sinT = (const float*)d_in[3];
    const float* Wq   = (const float*)d_in[4];
    const float* Wk   = (const float*)d_in[5];
    const float* Wv   = (const float*)d_in[6];
    const float* Wo   = (const float*)d_in[7];
    const float* qw   = (const float*)d_in[8];
    const float* kw   = (const float*)d_in[9];
    float* out = (float*)d_out;

    // workspace layout (bytes; ~111 MB total)
    char* ws = (char*)d_ws;
    _Float16* qkv  = (_Float16*)(ws);                      // 33,554,432  [4096][4096]
    _Float16* attn = (_Float16*)(ws + 33554432ull);        // 16,777,216  [4096][2048]
    _Float16* hidH = (_Float16*)(ws + 50331648ull);        // 20,971,520  [4096][2560]
    _Float16* wQKV = (_Float16*)(ws + 71303168ull);        // 20,971,520  [4096][2560]
    _Float16* woH  = (_Float16*)(ws + 92274688ull);        // 10,485,760  [2560][2048]
    _Float16* Vt   = (_Float16*)(ws + 102760448ull);       //  8,388,608  [B][NKV][D][S]

    // 0) all fp32 -> fp16 conversions in one launch
    conv_all<<<dim3(512, 5), 256, 0, stream>>>(
        hid, Wq, Wk, Wv, Wo,
        hidH, wQKV, wQKV + (size_t)2048 * 2560, wQKV + (size_t)3072 * 2560, woH);

    // 1) QKV projection (fp16 MFMA): -> fp16 [4096][4096]
    gemm_f16<0><<<dim3(32, 32), 256, 0, stream>>>(hidH, wQKV, qkv, 4096, 4096, 2560);
    // 2) in-place RMSNorm + RoPE on qkv
    rmsrope_inplace<<<4096, 256, 0, stream>>>(qkv, cosT, sinT, qw, kw);
    // 3) V transpose -> Vt [b][kvh][d][s]
    transpose_v<<<dim3(32, 4, 8), 256, 0, stream>>>(qkv, Vt);
    // 4) flash attention v3 (double-buffered async16 staging)
    attn_kernel<<<dim3(32, 8, 2), 256, 0, stream>>>(qkv, Vt, attn);
    // 5) output projection: fp16 [4096,2048] @ Wo^T -> fp32 out [4096][2560]
    gemm_f16<1><<<dim3(20, 32), 256, 0, stream>>>(attn, woH, out, 4096, 2560, 2048);
}